// Round 11
// baseline (396.198 us; speedup 1.0000x reference)
//
#include <hip/hip_runtime.h>
#include <hip/hip_bf16.h>

// ---------------------------------------------------------------------------
// GCN: h1 = lrelu(GCNConv(x; W1,b1)); h2 = lrelu(GCNConv(h1; W2,b2));
//      g = segment_mean(h2, batch); MLP head W3/W4/W5.
// R1-R6: see journal. R7 FAILED: B-from-global thrashed L1. R8 MOSTLY FAILED:
//   sub-histograms (count is atomic-pipe bound, not conflict bound).
// R9: GEMM LDS 52->35KB (As dropped, repack overlays Bs). Merged 90->87 only
//   -> count also not TLP-bound. Leave count alone.
// R10: agg5 = 2-deep edge unroll per group: pairs (e,e+4) stride 8, two
//   independent csr2->H chains + two accumulator sets -> 8 outstanding
//   256B gathers/wave (was 4). Latency-bound -> expect ~1.5x on agg.
// ---------------------------------------------------------------------------

#define SLOPE 0.01f

__device__ __forceinline__ float lrelu(float x) { return x > 0.f ? x : SLOPE * x; }

// bf16 helpers (RNE round, bit-shift expand)
__device__ __forceinline__ unsigned short f2bf(float f) {
    union { float f; unsigned u; } v; v.f = f;
    unsigned r = v.u + 0x7fffu + ((v.u >> 16) & 1u);
    return (unsigned short)(r >> 16);
}
__device__ __forceinline__ float bf2f(unsigned short h) {
    union { unsigned u; float f; } v; v.u = ((unsigned)h) << 16;
    return v.f;
}
__device__ __forceinline__ float bf_lo(unsigned x) {
    union { unsigned u; float f; } v; v.u = x << 16; return v.f;
}
__device__ __forceinline__ float bf_hi(unsigned x) {
    union { unsigned u; float f; } v; v.u = x & 0xffff0000u; return v.f;
}
__device__ __forceinline__ unsigned packbf(float lo, float hi) {
    return (unsigned)f2bf(lo) | ((unsigned)f2bf(hi) << 16);
}

typedef __attribute__((ext_vector_type(8))) short bf16x8;
typedef __attribute__((ext_vector_type(4))) float f32x4;

// ---- init: prepack W1^T, W2^T (bf16) + zero degi/gsum/gcnt ----------------
__global__ void k_init(int* __restrict__ zbase, int nz,
                       const float* __restrict__ W1, unsigned short* __restrict__ WT1,
                       const float* __restrict__ W2, unsigned short* __restrict__ WT2) {
    int b = blockIdx.x;
    if (b < 64) {
        int idx = b * 256 + threadIdx.x;
        int k = idx >> 7, n = idx & 127;
        WT1[n * 128 + k] = f2bf(W1[idx]);
    } else if (b < 128) {
        int idx = (b - 64) * 256 + threadIdx.x;
        int k = idx >> 7, n = idx & 127;
        WT2[n * 128 + k] = f2bf(W2[idx]);
    } else {
        int i = (b - 128) * 256 + threadIdx.x;
        if (i < nz) zbase[i] = 0;
    }
}

// ---- GEMM body R9: Bs in LDS; A direct from global; repack overlays Bs ----
#define LDA 136   // row pad +8 bf16: 2-way LDS aliasing only (free per m136)

template<bool IN_BF16>
__device__ __forceinline__ void gemm_body(const void* __restrict__ Xv,
                                          const unsigned short* __restrict__ WT,
                                          unsigned short* __restrict__ Y, int M,
                                          unsigned short* Bs, int bid) {
    int t = threadIdx.x;
    int row0 = bid * 64;
    int w = t >> 6, l = t & 63;
    int lr = l & 15;
    int ko = (l >> 4) * 8;

    // A fragments direct from global: wave = 16 rows x 64B contiguous lines
    int gr = row0 + w * 16 + lr;
    bool inb = gr < M;
    bf16x8 afr[4];
    if (IN_BF16) {
        const unsigned short* Xrow = (const unsigned short*)Xv + (size_t)gr * 128;
#pragma unroll
        for (int kc = 0; kc < 4; ++kc) {
            if (inb) afr[kc] = *(const bf16x8*)&Xrow[kc * 32 + ko];
            else     afr[kc] = (bf16x8){0, 0, 0, 0, 0, 0, 0, 0};
        }
    } else {
        const float* Xrow = (const float*)Xv + (size_t)gr * 128;
#pragma unroll
        for (int kc = 0; kc < 4; ++kc) {
            if (inb) {
                float4 u0 = *(const float4*)&Xrow[kc * 32 + ko];
                float4 u1 = *(const float4*)&Xrow[kc * 32 + ko + 4];
                union { bf16x8 v; unsigned u[4]; } cv;
                cv.u[0] = packbf(u0.x, u0.y);
                cv.u[1] = packbf(u0.z, u0.w);
                cv.u[2] = packbf(u1.x, u1.y);
                cv.u[3] = packbf(u1.z, u1.w);
                afr[kc] = cv.v;
            } else afr[kc] = (bf16x8){0, 0, 0, 0, 0, 0, 0, 0};
        }
    }

    // stage Bs (WT bf16, coalesced uint4)
    {
        const uint4* WT4 = (const uint4*)WT;
#pragma unroll
        for (int i = 0; i < 8; ++i) {
            int idx = t + i * 256;              // 2048 uint4
            int n = idx >> 4, c8 = idx & 15;
            *(uint4*)&Bs[n * LDA + c8 * 8] = WT4[idx];
        }
    }
    __syncthreads();

    f32x4 acc[8];
#pragma unroll
    for (int c = 0; c < 8; ++c) acc[c] = (f32x4){0.f, 0.f, 0.f, 0.f};

#pragma unroll
    for (int kc = 0; kc < 4; ++kc) {
        int kb = kc * 32 + ko;
        bf16x8 bfr[8];
#pragma unroll
        for (int ct = 0; ct < 8; ++ct)
            bfr[ct] = *(const bf16x8*)&Bs[(ct * 16 + lr) * LDA + kb];
#pragma unroll
        for (int ct = 0; ct < 8; ++ct)
            acc[ct] = __builtin_amdgcn_mfma_f32_16x16x32_bf16(afr[kc], bfr[ct], acc[ct], 0, 0, 0);
    }

    // repack D tile through LDS (overlays Bs -- k-loop reads are done)
    __syncthreads();
    int qr = (l >> 4) * 4;
#pragma unroll
    for (int i = 0; i < 4; ++i) {
        int r = w * 16 + qr + i;
#pragma unroll
        for (int ct = 0; ct < 8; ++ct)
            Bs[r * LDA + ct * 16 + lr] = f2bf(acc[ct][i]);
    }
    __syncthreads();
    {
        uint4* Y4 = (uint4*)Y;
#pragma unroll
        for (int i = 0; i < 4; ++i) {
            int idx = t + i * 256;
            int r = idx >> 4, c8 = idx & 15;
            int g2 = row0 + r;
            if (g2 < M) Y4[(size_t)g2 * 16 + c8] = *(const uint4*)&Bs[r * LDA + c8 * 8];
        }
    }
}

// ---- count (8 edges/thread, atomicAdd return = in-bucket position) --------
__device__ __forceinline__ void count_body(const int* __restrict__ dst,
                                           int* __restrict__ degi,
                                           int* __restrict__ pos, int E, int bid) {
    int i = bid * 256 + threadIdx.x;
    int e = i * 8;
    if (e + 7 < E) {
        int4 d0 = *(const int4*)&dst[e];
        int4 d1 = *(const int4*)&dst[e + 4];
        int4 p0, p1;
        p0.x = atomicAdd(&degi[d0.x], 1);
        p0.y = atomicAdd(&degi[d0.y], 1);
        p0.z = atomicAdd(&degi[d0.z], 1);
        p0.w = atomicAdd(&degi[d0.w], 1);
        p1.x = atomicAdd(&degi[d1.x], 1);
        p1.y = atomicAdd(&degi[d1.y], 1);
        p1.z = atomicAdd(&degi[d1.z], 1);
        p1.w = atomicAdd(&degi[d1.w], 1);
        *(int4*)&pos[e]     = p0;
        *(int4*)&pos[e + 4] = p1;
    } else {
        for (; e < E; ++e) pos[e] = atomicAdd(&degi[dst[e]], 1);
    }
}

// ---- merged: CSR count (blocks 0..nbC-1) + GEMM layer 1 (rest) ------------
__global__ __launch_bounds__(256) void k_count_gemm1(
    const int* __restrict__ dst, int* __restrict__ degi, int* __restrict__ pos,
    int E, int nbC,
    const float* __restrict__ X, const unsigned short* __restrict__ WT,
    unsigned short* __restrict__ Y, int M) {
    __shared__ unsigned short Bs[128 * LDA];   // 34.8 KB total
    int b = blockIdx.x;
    if (b < nbC) count_body(dst, degi, pos, E, b);
    else gemm_body<false>((const void*)X, WT, Y, M, Bs, b - nbC);
}

__global__ __launch_bounds__(256) void k_gemm2(
    const void* __restrict__ Xv, const unsigned short* __restrict__ WT,
    unsigned short* __restrict__ Y, int M) {
    __shared__ unsigned short Bs[128 * LDA];
    gemm_body<true>(Xv, WT, Y, M, Bs, blockIdx.x);
}

// ---- exclusive scan of (degi+1) -> rp (+1 self-loop slot); dinv folded ----
__global__ void k_scan1(const int* __restrict__ degi, int* __restrict__ rp,
                        int* __restrict__ bsum, float* __restrict__ dinv, int N) {
    __shared__ int s[256];
    int t = threadIdx.x;
    int i = blockIdx.x * 256 + t;
    int v = (i < N) ? (degi[i] + 1) : 0;
    s[t] = v;
    __syncthreads();
    for (int off = 1; off < 256; off <<= 1) {
        int add = (t >= off) ? s[t - off] : 0;
        __syncthreads();
        s[t] += add;
        __syncthreads();
    }
    if (i < N) {
        rp[i] = s[t] - v;
        dinv[i] = rsqrtf((float)v);   // v = deg+1
    }
    if (t == 255) bsum[blockIdx.x] = s[255];
}

__global__ void k_scan2(int* __restrict__ bsum, int nb) {
    __shared__ int s[512];
    int t = threadIdx.x;
    int v = (t < nb) ? bsum[t] : 0;
    s[t] = v;
    __syncthreads();
    for (int off = 1; off < 512; off <<= 1) {
        int add = (t >= off) ? s[t - off] : 0;
        __syncthreads();
        s[t] += add;
        __syncthreads();
    }
    if (t < nb) bsum[t] = s[t] - v;
}

__global__ void k_scan3(int* __restrict__ rp, const int* __restrict__ bsum,
                        int N, int Etot) {
    int i = blockIdx.x * 256 + threadIdx.x;
    if (i < N) rp[i] += bsum[blockIdx.x];
    if (blockIdx.x == 0 && threadIdx.x == 0) rp[N] = Etot;
}

// ---- merged: fill (4 edges/thread) + self-loop edges ----------------------
__global__ void k_fill_self(const int* __restrict__ src, const int* __restrict__ dst,
                            const int* __restrict__ pos, const int* __restrict__ rp,
                            const float* __restrict__ dinv,
                            int2* __restrict__ csr2, int E, int nbF, int N) {
    int b = blockIdx.x;
    if (b < nbF) {
        int i = b * 256 + threadIdx.x;
        int e = i * 4;
        if (e + 3 < E) {
            int4 s = *(const int4*)&src[e];
            int4 d = *(const int4*)&dst[e];
            int4 p = *(const int4*)&pos[e];
            float wx = dinv[s.x] * dinv[d.x];
            float wy = dinv[s.y] * dinv[d.y];
            float wz = dinv[s.z] * dinv[d.z];
            float ww = dinv[s.w] * dinv[d.w];
            csr2[rp[d.x] + p.x] = make_int2(s.x, __float_as_int(wx));
            csr2[rp[d.y] + p.y] = make_int2(s.y, __float_as_int(wy));
            csr2[rp[d.z] + p.z] = make_int2(s.z, __float_as_int(wz));
            csr2[rp[d.w] + p.w] = make_int2(s.w, __float_as_int(ww));
        } else {
            for (; e < E; ++e) {
                float wv = dinv[src[e]] * dinv[dst[e]];
                csr2[rp[dst[e]] + pos[e]] = make_int2(src[e], __float_as_int(wv));
            }
        }
    } else {
        int i = (b - nbF) * 256 + threadIdx.x;
        if (i < N) {
            float d = dinv[i];
            csr2[rp[i + 1] - 1] = make_int2(i, __float_as_int(d * d));  // self slot
        }
    }
}

// ---- aggregation R10: wave-per-node, 2-deep edge unroll per group ---------
// 4 groups x 16 lanes; each group walks pairs (e, e+4) stride 8 -> two
// independent csr2->H chains, 8 outstanding 256B gathers per wave.
__global__ __launch_bounds__(256) void k_agg5(const unsigned short* __restrict__ H,
                                              const int2* __restrict__ csr2,
                                              const int* __restrict__ rp,
                                              const float* __restrict__ bias,
                                              unsigned short* __restrict__ OUT, int N) {
    int l = threadIdx.x & 63;
    int u = blockIdx.x * 4 + (threadIdx.x >> 6);
    if (u >= N) return;
    int g = l >> 4, cl = l & 15;
    int e0 = rp[u], e1 = rp[u + 1];
    const uint4* H4 = (const uint4*)H;

    float a0 = 0.f, a1 = 0.f, a2 = 0.f, a3 = 0.f;
    float a4 = 0.f, a5 = 0.f, a6 = 0.f, a7 = 0.f;
    float b0 = 0.f, b1_ = 0.f, b2_ = 0.f, b3_ = 0.f;
    float b4_ = 0.f, b5_ = 0.f, b6_ = 0.f, b7_ = 0.f;

    int e = e0 + g;
    int2 cA = make_int2(0, 0), cB = make_int2(0, 0);
    if (e < e1) cA = csr2[e];
    if (e + 4 < e1) cB = csr2[e + 4];
    while (e < e1) {
        int2 uA = cA, uB = cB;
        bool doB = (e + 4) < e1;
        int en = e + 8;
        if (en < e1) cA = csr2[en];
        if (en + 4 < e1) cB = csr2[en + 4];
        {
            float w = __int_as_float(uA.y);
            uint4 hv = H4[(size_t)uA.x * 16 + cl];
            a0 += w * bf_lo(hv.x); a1 += w * bf_hi(hv.x);
            a2 += w * bf_lo(hv.y); a3 += w * bf_hi(hv.y);
            a4 += w * bf_lo(hv.z); a5 += w * bf_hi(hv.z);
            a6 += w * bf_lo(hv.w); a7 += w * bf_hi(hv.w);
        }
        if (doB) {
            float w = __int_as_float(uB.y);
            uint4 hv = H4[(size_t)uB.x * 16 + cl];
            b0  += w * bf_lo(hv.x); b1_ += w * bf_hi(hv.x);
            b2_ += w * bf_lo(hv.y); b3_ += w * bf_hi(hv.y);
            b4_ += w * bf_lo(hv.z); b5_ += w * bf_hi(hv.z);
            b6_ += w * bf_lo(hv.w); b7_ += w * bf_hi(hv.w);
        }
        e = en;
    }
    a0 += b0;  a1 += b1_; a2 += b2_; a3 += b3_;
    a4 += b4_; a5 += b5_; a6 += b6_; a7 += b7_;

    a0 += __shfl_xor(a0, 16); a0 += __shfl_xor(a0, 32);
    a1 += __shfl_xor(a1, 16); a1 += __shfl_xor(a1, 32);
    a2 += __shfl_xor(a2, 16); a2 += __shfl_xor(a2, 32);
    a3 += __shfl_xor(a3, 16); a3 += __shfl_xor(a3, 32);
    a4 += __shfl_xor(a4, 16); a4 += __shfl_xor(a4, 32);
    a5 += __shfl_xor(a5, 16); a5 += __shfl_xor(a5, 32);
    a6 += __shfl_xor(a6, 16); a6 += __shfl_xor(a6, 32);
    a7 += __shfl_xor(a7, 16); a7 += __shfl_xor(a7, 32);

    if (g == 0) {
        float4 c0 = *(const float4*)&bias[cl * 8];
        float4 c1 = *(const float4*)&bias[cl * 8 + 4];
        uint4 o;
        o.x = packbf(lrelu(a0 + c0.x), lrelu(a1 + c0.y));
        o.y = packbf(lrelu(a2 + c0.z), lrelu(a3 + c0.w));
        o.z = packbf(lrelu(a4 + c1.x), lrelu(a5 + c1.y));
        o.w = packbf(lrelu(a6 + c1.z), lrelu(a7 + c1.w));
        ((uint4*)OUT)[(size_t)u * 16 + cl] = o;
    }
}

// ---- pool: 4 node-streams x 64 lanes (uint = 2ch), run-accumulate ---------
#define PCH 128
__global__ __launch_bounds__(256) void k_pool3(const unsigned short* __restrict__ H,
                                               const int* __restrict__ batch,
                                               float* __restrict__ Gsum,
                                               int* __restrict__ Gcnt, int N) {
    int t = threadIdx.x;
    int st = t >> 6, c2 = t & 63;     // stream 0..3, channel pair 0..63
    int n0 = blockIdx.x * PCH + st * (PCH / 4);
    int n1 = n0 + (PCH / 4); if (n1 > N) n1 = N;
    if (n0 >= N) return;
    float a0 = 0.f, a1 = 0.f;
    int cur = batch[n0], runstart = n0;
    for (int n = n0; n < n1; ++n) {
        int g = batch[n];
        if (g != cur) {
            atomicAdd(&Gsum[cur * 128 + c2 * 2], a0);
            atomicAdd(&Gsum[cur * 128 + c2 * 2 + 1], a1);
            if (c2 == 0) atomicAdd(&Gcnt[cur], n - runstart);
            a0 = a1 = 0.f; cur = g; runstart = n;
        }
        unsigned hv = *(const unsigned*)&H[(size_t)n * 128 + c2 * 2];
        a0 += bf_lo(hv); a1 += bf_hi(hv);
    }
    atomicAdd(&Gsum[cur * 128 + c2 * 2], a0);
    atomicAdd(&Gsum[cur * 128 + c2 * 2 + 1], a1);
    if (c2 == 0) atomicAdd(&Gcnt[cur], n1 - runstart);
}

// ---- fused MLP head (divide-by-count folded in): one graph per block ------
__global__ __launch_bounds__(64) void k_mlp(const float* __restrict__ Gsum,
                                            const int* __restrict__ Gcnt,
                                            const float* __restrict__ W3, const float* __restrict__ b3,
                                            const float* __restrict__ W4, const float* __restrict__ b4,
                                            const float* __restrict__ W5, const float* __restrict__ b5,
                                            float* __restrict__ OUT) {
    __shared__ float row[128];
    __shared__ float t1[64];
    __shared__ float t2[64];
    int g = blockIdx.x, t = threadIdx.x;
    float inv = 1.0f / fmaxf((float)Gcnt[g], 1.0f);
    row[t]      = Gsum[g * 128 + t] * inv;
    row[t + 64] = Gsum[g * 128 + t + 64] * inv;
    __syncthreads();
    float acc = b3[t];
    for (int k = 0; k < 128; ++k) acc += row[k] * W3[k * 64 + t];
    t1[t] = lrelu(acc);
    __syncthreads();
    acc = b4[t];
    for (int k = 0; k < 64; ++k) acc += t1[k] * W4[k * 64 + t];
    t2[t] = lrelu(acc);
    __syncthreads();
    if (t < 10) {
        acc = b5[t];
        for (int k = 0; k < 64; ++k) acc += t2[k] * W5[k * 10 + t];
        OUT[g * 10 + t] = acc;
    }
}

// ---------------------------------------------------------------------------

extern "C" void kernel_launch(void* const* d_in, const int* in_sizes, int n_in,
                              void* d_out, int out_size, void* d_ws, size_t ws_size,
                              hipStream_t stream) {
    const float* x    = (const float*)d_in[0];
    const int*   ei   = (const int*)d_in[1];   // [2, E] int32
    const int*   batch= (const int*)d_in[2];
    const float* W1   = (const float*)d_in[3];
    const float* b1   = (const float*)d_in[4];
    const float* W2   = (const float*)d_in[5];
    const float* b2   = (const float*)d_in[6];
    const float* W3   = (const float*)d_in[7];
    const float* b3   = (const float*)d_in[8];
    const float* W4   = (const float*)d_in[9];
    const float* b4   = (const float*)d_in[10];
    const float* W5   = (const float*)d_in[11];
    const float* b5   = (const float*)d_in[12];
    float* out = (float*)d_out;

    const int N = in_sizes[2];          // 100000
    const int E = in_sizes[1] / 2;      // 1600000
    const int NG = 128;                 // NUM_GRAPHS

    const int* src = ei;
    const int* dst = ei + E;

    // workspace carve-up  (degi, gsum, gcnt contiguous -> one zero pass)
    char* w = (char*)d_ws;
    unsigned short* bufA = (unsigned short*)w; w += (size_t)N * 128 * 2;  // 25.6 MB
    unsigned short* bufB = (unsigned short*)w; w += (size_t)N * 128 * 2;  // 25.6 MB
    int*   degi = (int*)w;   w += (size_t)N * 4;
    float* gsum = (float*)w; w += (size_t)NG * 128 * 4;
    int*   gcnt = (int*)w;   w += (size_t)NG * 4;
    float* dinv = (float*)w; w += (size_t)N * 4;
    int*   rp   = (int*)w;   w += (size_t)(N + 8) * 4;
    int*   bsum = (int*)w;   w += 512 * 4;
    int2*  csr2 = (int2*)w;  w += (size_t)(E + N) * 8;   // 13.6 MB
    int*   pos  = (int*)w;   w += (size_t)E * 4;         // 6.4 MB
    unsigned short* WT1 = (unsigned short*)w; w += 128 * 128 * 2;
    unsigned short* WT2 = (unsigned short*)w; w += 128 * 128 * 2;
    (void)ws_size; (void)n_in; (void)out_size;

    int nbN  = (N + 255) / 256;       // 391
    int nbE4 = (E / 4 + 255) / 256;   // 1563 (fill)
    int nbE8 = (E / 8 + 255) / 256;   // 782  (count)
    int nbG  = (N + 63) / 64;         // 1563 (gemm)
    int nZero = N + NG * 128 + NG;
    int nbZ  = (nZero + 255) / 256;

    // init: W prepack + zero accumulators
    k_init<<<128 + nbZ, 256, 0, stream>>>(degi, nZero, W1, WT1, W2, WT2);
    // CSR count overlapped with GEMM layer 1 (independent)
    k_count_gemm1<<<nbE8 + nbG, 256, 0, stream>>>(dst, degi, pos, E, nbE8,
                                                  x, WT1, bufA, N);
    k_scan1<<<nbN, 256, 0, stream>>>(degi, rp, bsum, dinv, N);
    k_scan2<<<1, 512, 0, stream>>>(bsum, nbN);
    k_scan3<<<nbN, 256, 0, stream>>>(rp, bsum, N, E + N);
    k_fill_self<<<nbE4 + nbN, 256, 0, stream>>>(src, dst, pos, rp, dinv,
                                                csr2, E, nbE4, N);

    int nbA = (N + 3) / 4;            // 25000 agg blocks (4 waves = 4 nodes)

    // layer 1 aggregate, layer 2 gemm + aggregate
    k_agg5<<<nbA, 256, 0, stream>>>(bufA, csr2, rp, b1, bufB, N);
    k_gemm2<<<nbG, 256, 0, stream>>>(bufB, WT2, bufA, N);
    k_agg5<<<nbA, 256, 0, stream>>>(bufA, csr2, rp, b2, bufB, N);

    // pool + MLP head
    int nbP = (N + PCH - 1) / PCH;    // 782
    k_pool3<<<nbP, 256, 0, stream>>>(bufB, batch, gsum, gcnt, N);
    k_mlp<<<NG, 64, 0, stream>>>(gsum, gcnt, W3, b3, W4, b4, W5, b5, out);
}

// Round 12
// 387.789 us; speedup vs baseline: 1.0217x; 1.0217x over previous
//
#include <hip/hip_runtime.h>
#include <hip/hip_bf16.h>

// ---------------------------------------------------------------------------
// GCN: h1 = lrelu(GCNConv(x; W1,b1)); h2 = lrelu(GCNConv(h1; W2,b2));
//      g = segment_mean(h2, batch); MLP head W3/W4/W5.
// R1-R10: see journal. Key structural findings:
//   - agg plateaued ~70us/layer (gather-pattern bound; unrolls neutral).
//   - count is atomic-PIPE bound (~13 atomics/cy device-wide): address
//     spreading (R8) and more waves (R9) both ~neutral.
//   - merged count+gemm1 showed ZERO overlap: 782 latency-crawling count
//     blocks held ~3/4 of all block slots for the whole window.
// R11: dense count -- 98 blocks x 16384 edges (8 iters x 8 edges/thread).
//   Atomic pipe still saturated, but count now occupies ~98 slots; the 1563
//   gemm blocks run concurrently at full speed. Expect merged 87 -> ~60.
// ---------------------------------------------------------------------------

#define SLOPE 0.01f

__device__ __forceinline__ float lrelu(float x) { return x > 0.f ? x : SLOPE * x; }

// bf16 helpers (RNE round, bit-shift expand)
__device__ __forceinline__ unsigned short f2bf(float f) {
    union { float f; unsigned u; } v; v.f = f;
    unsigned r = v.u + 0x7fffu + ((v.u >> 16) & 1u);
    return (unsigned short)(r >> 16);
}
__device__ __forceinline__ float bf2f(unsigned short h) {
    union { unsigned u; float f; } v; v.u = ((unsigned)h) << 16;
    return v.f;
}
__device__ __forceinline__ float bf_lo(unsigned x) {
    union { unsigned u; float f; } v; v.u = x << 16; return v.f;
}
__device__ __forceinline__ float bf_hi(unsigned x) {
    union { unsigned u; float f; } v; v.u = x & 0xffff0000u; return v.f;
}
__device__ __forceinline__ unsigned packbf(float lo, float hi) {
    return (unsigned)f2bf(lo) | ((unsigned)f2bf(hi) << 16);
}

typedef __attribute__((ext_vector_type(8))) short bf16x8;
typedef __attribute__((ext_vector_type(4))) float f32x4;

// ---- init: prepack W1^T, W2^T (bf16) + zero degi/gsum/gcnt ----------------
__global__ void k_init(int* __restrict__ zbase, int nz,
                       const float* __restrict__ W1, unsigned short* __restrict__ WT1,
                       const float* __restrict__ W2, unsigned short* __restrict__ WT2) {
    int b = blockIdx.x;
    if (b < 64) {
        int idx = b * 256 + threadIdx.x;
        int k = idx >> 7, n = idx & 127;
        WT1[n * 128 + k] = f2bf(W1[idx]);
    } else if (b < 128) {
        int idx = (b - 64) * 256 + threadIdx.x;
        int k = idx >> 7, n = idx & 127;
        WT2[n * 128 + k] = f2bf(W2[idx]);
    } else {
        int i = (b - 128) * 256 + threadIdx.x;
        if (i < nz) zbase[i] = 0;
    }
}

// ---- GEMM body R9: Bs in LDS; A direct from global; repack overlays Bs ----
#define LDA 136   // row pad +8 bf16: 2-way LDS aliasing only (free per m136)

template<bool IN_BF16>
__device__ __forceinline__ void gemm_body(const void* __restrict__ Xv,
                                          const unsigned short* __restrict__ WT,
                                          unsigned short* __restrict__ Y, int M,
                                          unsigned short* Bs, int bid) {
    int t = threadIdx.x;
    int row0 = bid * 64;
    int w = t >> 6, l = t & 63;
    int lr = l & 15;
    int ko = (l >> 4) * 8;

    // A fragments direct from global: wave = 16 rows x 64B contiguous lines
    int gr = row0 + w * 16 + lr;
    bool inb = gr < M;
    bf16x8 afr[4];
    if (IN_BF16) {
        const unsigned short* Xrow = (const unsigned short*)Xv + (size_t)gr * 128;
#pragma unroll
        for (int kc = 0; kc < 4; ++kc) {
            if (inb) afr[kc] = *(const bf16x8*)&Xrow[kc * 32 + ko];
            else     afr[kc] = (bf16x8){0, 0, 0, 0, 0, 0, 0, 0};
        }
    } else {
        const float* Xrow = (const float*)Xv + (size_t)gr * 128;
#pragma unroll
        for (int kc = 0; kc < 4; ++kc) {
            if (inb) {
                float4 u0 = *(const float4*)&Xrow[kc * 32 + ko];
                float4 u1 = *(const float4*)&Xrow[kc * 32 + ko + 4];
                union { bf16x8 v; unsigned u[4]; } cv;
                cv.u[0] = packbf(u0.x, u0.y);
                cv.u[1] = packbf(u0.z, u0.w);
                cv.u[2] = packbf(u1.x, u1.y);
                cv.u[3] = packbf(u1.z, u1.w);
                afr[kc] = cv.v;
            } else afr[kc] = (bf16x8){0, 0, 0, 0, 0, 0, 0, 0};
        }
    }

    // stage Bs (WT bf16, coalesced uint4)
    {
        const uint4* WT4 = (const uint4*)WT;
#pragma unroll
        for (int i = 0; i < 8; ++i) {
            int idx = t + i * 256;              // 2048 uint4
            int n = idx >> 4, c8 = idx & 15;
            *(uint4*)&Bs[n * LDA + c8 * 8] = WT4[idx];
        }
    }
    __syncthreads();

    f32x4 acc[8];
#pragma unroll
    for (int c = 0; c < 8; ++c) acc[c] = (f32x4){0.f, 0.f, 0.f, 0.f};

#pragma unroll
    for (int kc = 0; kc < 4; ++kc) {
        int kb = kc * 32 + ko;
        bf16x8 bfr[8];
#pragma unroll
        for (int ct = 0; ct < 8; ++ct)
            bfr[ct] = *(const bf16x8*)&Bs[(ct * 16 + lr) * LDA + kb];
#pragma unroll
        for (int ct = 0; ct < 8; ++ct)
            acc[ct] = __builtin_amdgcn_mfma_f32_16x16x32_bf16(afr[kc], bfr[ct], acc[ct], 0, 0, 0);
    }

    // repack D tile through LDS (overlays Bs -- k-loop reads are done)
    __syncthreads();
    int qr = (l >> 4) * 4;
#pragma unroll
    for (int i = 0; i < 4; ++i) {
        int r = w * 16 + qr + i;
#pragma unroll
        for (int ct = 0; ct < 8; ++ct)
            Bs[r * LDA + ct * 16 + lr] = f2bf(acc[ct][i]);
    }
    __syncthreads();
    {
        uint4* Y4 = (uint4*)Y;
#pragma unroll
        for (int i = 0; i < 4; ++i) {
            int idx = t + i * 256;
            int r = idx >> 4, c8 = idx & 15;
            int g2 = row0 + r;
            if (g2 < M) Y4[(size_t)g2 * 16 + c8] = *(const uint4*)&Bs[r * LDA + c8 * 8];
        }
    }
}

// ---- count R11: DENSE -- 16384 edges/block (8 iters x 8 edges/thread) -----
// Saturates the atomic pipe with ~98 blocks so co-scheduled gemm blocks get
// the remaining ~900 block slots (overlap was zero with 782 crawler blocks).
#define CEB 16384   // edges per count block
__device__ __forceinline__ void count_body(const int* __restrict__ dst,
                                           int* __restrict__ degi,
                                           int* __restrict__ pos, int E, int bid) {
    int base = bid * CEB;
#pragma unroll
    for (int j = 0; j < 8; ++j) {
        int e = base + j * 2048 + threadIdx.x * 8;
        if (e + 7 < E) {
            int4 d0 = *(const int4*)&dst[e];
            int4 d1 = *(const int4*)&dst[e + 4];
            int4 p0, p1;
            p0.x = atomicAdd(&degi[d0.x], 1);
            p0.y = atomicAdd(&degi[d0.y], 1);
            p0.z = atomicAdd(&degi[d0.z], 1);
            p0.w = atomicAdd(&degi[d0.w], 1);
            p1.x = atomicAdd(&degi[d1.x], 1);
            p1.y = atomicAdd(&degi[d1.y], 1);
            p1.z = atomicAdd(&degi[d1.z], 1);
            p1.w = atomicAdd(&degi[d1.w], 1);
            *(int4*)&pos[e]     = p0;
            *(int4*)&pos[e + 4] = p1;
        } else {
            for (int k = e; k < E && k < e + 8; ++k)
                pos[k] = atomicAdd(&degi[dst[k]], 1);
        }
    }
}

// ---- merged: CSR count (blocks 0..nbC-1) + GEMM layer 1 (rest) ------------
__global__ __launch_bounds__(256) void k_count_gemm1(
    const int* __restrict__ dst, int* __restrict__ degi, int* __restrict__ pos,
    int E, int nbC,
    const float* __restrict__ X, const unsigned short* __restrict__ WT,
    unsigned short* __restrict__ Y, int M) {
    __shared__ unsigned short Bs[128 * LDA];   // 34.8 KB total
    int b = blockIdx.x;
    if (b < nbC) count_body(dst, degi, pos, E, b);
    else gemm_body<false>((const void*)X, WT, Y, M, Bs, b - nbC);
}

__global__ __launch_bounds__(256) void k_gemm2(
    const void* __restrict__ Xv, const unsigned short* __restrict__ WT,
    unsigned short* __restrict__ Y, int M) {
    __shared__ unsigned short Bs[128 * LDA];
    gemm_body<true>(Xv, WT, Y, M, Bs, blockIdx.x);
}

// ---- exclusive scan of (degi+1) -> rp (+1 self-loop slot); dinv folded ----
__global__ void k_scan1(const int* __restrict__ degi, int* __restrict__ rp,
                        int* __restrict__ bsum, float* __restrict__ dinv, int N) {
    __shared__ int s[256];
    int t = threadIdx.x;
    int i = blockIdx.x * 256 + t;
    int v = (i < N) ? (degi[i] + 1) : 0;
    s[t] = v;
    __syncthreads();
    for (int off = 1; off < 256; off <<= 1) {
        int add = (t >= off) ? s[t - off] : 0;
        __syncthreads();
        s[t] += add;
        __syncthreads();
    }
    if (i < N) {
        rp[i] = s[t] - v;
        dinv[i] = rsqrtf((float)v);   // v = deg+1
    }
    if (t == 255) bsum[blockIdx.x] = s[255];
}

__global__ void k_scan2(int* __restrict__ bsum, int nb) {
    __shared__ int s[512];
    int t = threadIdx.x;
    int v = (t < nb) ? bsum[t] : 0;
    s[t] = v;
    __syncthreads();
    for (int off = 1; off < 512; off <<= 1) {
        int add = (t >= off) ? s[t - off] : 0;
        __syncthreads();
        s[t] += add;
        __syncthreads();
    }
    if (t < nb) bsum[t] = s[t] - v;
}

__global__ void k_scan3(int* __restrict__ rp, const int* __restrict__ bsum,
                        int N, int Etot) {
    int i = blockIdx.x * 256 + threadIdx.x;
    if (i < N) rp[i] += bsum[blockIdx.x];
    if (blockIdx.x == 0 && threadIdx.x == 0) rp[N] = Etot;
}

// ---- merged: fill (4 edges/thread) + self-loop edges ----------------------
__global__ void k_fill_self(const int* __restrict__ src, const int* __restrict__ dst,
                            const int* __restrict__ pos, const int* __restrict__ rp,
                            const float* __restrict__ dinv,
                            int2* __restrict__ csr2, int E, int nbF, int N) {
    int b = blockIdx.x;
    if (b < nbF) {
        int i = b * 256 + threadIdx.x;
        int e = i * 4;
        if (e + 3 < E) {
            int4 s = *(const int4*)&src[e];
            int4 d = *(const int4*)&dst[e];
            int4 p = *(const int4*)&pos[e];
            float wx = dinv[s.x] * dinv[d.x];
            float wy = dinv[s.y] * dinv[d.y];
            float wz = dinv[s.z] * dinv[d.z];
            float ww = dinv[s.w] * dinv[d.w];
            csr2[rp[d.x] + p.x] = make_int2(s.x, __float_as_int(wx));
            csr2[rp[d.y] + p.y] = make_int2(s.y, __float_as_int(wy));
            csr2[rp[d.z] + p.z] = make_int2(s.z, __float_as_int(wz));
            csr2[rp[d.w] + p.w] = make_int2(s.w, __float_as_int(ww));
        } else {
            for (; e < E; ++e) {
                float wv = dinv[src[e]] * dinv[dst[e]];
                csr2[rp[dst[e]] + pos[e]] = make_int2(src[e], __float_as_int(wv));
            }
        }
    } else {
        int i = (b - nbF) * 256 + threadIdx.x;
        if (i < N) {
            float d = dinv[i];
            csr2[rp[i + 1] - 1] = make_int2(i, __float_as_int(d * d));  // self slot
        }
    }
}

// ---- aggregation: wave-per-node, 2-deep edge unroll per group -------------
__global__ __launch_bounds__(256) void k_agg5(const unsigned short* __restrict__ H,
                                              const int2* __restrict__ csr2,
                                              const int* __restrict__ rp,
                                              const float* __restrict__ bias,
                                              unsigned short* __restrict__ OUT, int N) {
    int l = threadIdx.x & 63;
    int u = blockIdx.x * 4 + (threadIdx.x >> 6);
    if (u >= N) return;
    int g = l >> 4, cl = l & 15;
    int e0 = rp[u], e1 = rp[u + 1];
    const uint4* H4 = (const uint4*)H;

    float a0 = 0.f, a1 = 0.f, a2 = 0.f, a3 = 0.f;
    float a4 = 0.f, a5 = 0.f, a6 = 0.f, a7 = 0.f;
    float b0 = 0.f, b1_ = 0.f, b2_ = 0.f, b3_ = 0.f;
    float b4_ = 0.f, b5_ = 0.f, b6_ = 0.f, b7_ = 0.f;

    int e = e0 + g;
    int2 cA = make_int2(0, 0), cB = make_int2(0, 0);
    if (e < e1) cA = csr2[e];
    if (e + 4 < e1) cB = csr2[e + 4];
    while (e < e1) {
        int2 uA = cA, uB = cB;
        bool doB = (e + 4) < e1;
        int en = e + 8;
        if (en < e1) cA = csr2[en];
        if (en + 4 < e1) cB = csr2[en + 4];
        {
            float w = __int_as_float(uA.y);
            uint4 hv = H4[(size_t)uA.x * 16 + cl];
            a0 += w * bf_lo(hv.x); a1 += w * bf_hi(hv.x);
            a2 += w * bf_lo(hv.y); a3 += w * bf_hi(hv.y);
            a4 += w * bf_lo(hv.z); a5 += w * bf_hi(hv.z);
            a6 += w * bf_lo(hv.w); a7 += w * bf_hi(hv.w);
        }
        if (doB) {
            float w = __int_as_float(uB.y);
            uint4 hv = H4[(size_t)uB.x * 16 + cl];
            b0  += w * bf_lo(hv.x); b1_ += w * bf_hi(hv.x);
            b2_ += w * bf_lo(hv.y); b3_ += w * bf_hi(hv.y);
            b4_ += w * bf_lo(hv.z); b5_ += w * bf_hi(hv.z);
            b6_ += w * bf_lo(hv.w); b7_ += w * bf_hi(hv.w);
        }
        e = en;
    }
    a0 += b0;  a1 += b1_; a2 += b2_; a3 += b3_;
    a4 += b4_; a5 += b5_; a6 += b6_; a7 += b7_;

    a0 += __shfl_xor(a0, 16); a0 += __shfl_xor(a0, 32);
    a1 += __shfl_xor(a1, 16); a1 += __shfl_xor(a1, 32);
    a2 += __shfl_xor(a2, 16); a2 += __shfl_xor(a2, 32);
    a3 += __shfl_xor(a3, 16); a3 += __shfl_xor(a3, 32);
    a4 += __shfl_xor(a4, 16); a4 += __shfl_xor(a4, 32);
    a5 += __shfl_xor(a5, 16); a5 += __shfl_xor(a5, 32);
    a6 += __shfl_xor(a6, 16); a6 += __shfl_xor(a6, 32);
    a7 += __shfl_xor(a7, 16); a7 += __shfl_xor(a7, 32);

    if (g == 0) {
        float4 c0 = *(const float4*)&bias[cl * 8];
        float4 c1 = *(const float4*)&bias[cl * 8 + 4];
        uint4 o;
        o.x = packbf(lrelu(a0 + c0.x), lrelu(a1 + c0.y));
        o.y = packbf(lrelu(a2 + c0.z), lrelu(a3 + c0.w));
        o.z = packbf(lrelu(a4 + c1.x), lrelu(a5 + c1.y));
        o.w = packbf(lrelu(a6 + c1.z), lrelu(a7 + c1.w));
        ((uint4*)OUT)[(size_t)u * 16 + cl] = o;
    }
}

// ---- pool: 4 node-streams x 64 lanes (uint = 2ch), run-accumulate ---------
#define PCH 128
__global__ __launch_bounds__(256) void k_pool3(const unsigned short* __restrict__ H,
                                               const int* __restrict__ batch,
                                               float* __restrict__ Gsum,
                                               int* __restrict__ Gcnt, int N) {
    int t = threadIdx.x;
    int st = t >> 6, c2 = t & 63;     // stream 0..3, channel pair 0..63
    int n0 = blockIdx.x * PCH + st * (PCH / 4);
    int n1 = n0 + (PCH / 4); if (n1 > N) n1 = N;
    if (n0 >= N) return;
    float a0 = 0.f, a1 = 0.f;
    int cur = batch[n0], runstart = n0;
    for (int n = n0; n < n1; ++n) {
        int g = batch[n];
        if (g != cur) {
            atomicAdd(&Gsum[cur * 128 + c2 * 2], a0);
            atomicAdd(&Gsum[cur * 128 + c2 * 2 + 1], a1);
            if (c2 == 0) atomicAdd(&Gcnt[cur], n - runstart);
            a0 = a1 = 0.f; cur = g; runstart = n;
        }
        unsigned hv = *(const unsigned*)&H[(size_t)n * 128 + c2 * 2];
        a0 += bf_lo(hv); a1 += bf_hi(hv);
    }
    atomicAdd(&Gsum[cur * 128 + c2 * 2], a0);
    atomicAdd(&Gsum[cur * 128 + c2 * 2 + 1], a1);
    if (c2 == 0) atomicAdd(&Gcnt[cur], n1 - runstart);
}

// ---- fused MLP head (divide-by-count folded in): one graph per block ------
__global__ __launch_bounds__(64) void k_mlp(const float* __restrict__ Gsum,
                                            const int* __restrict__ Gcnt,
                                            const float* __restrict__ W3, const float* __restrict__ b3,
                                            const float* __restrict__ W4, const float* __restrict__ b4,
                                            const float* __restrict__ W5, const float* __restrict__ b5,
                                            float* __restrict__ OUT) {
    __shared__ float row[128];
    __shared__ float t1[64];
    __shared__ float t2[64];
    int g = blockIdx.x, t = threadIdx.x;
    float inv = 1.0f / fmaxf((float)Gcnt[g], 1.0f);
    row[t]      = Gsum[g * 128 + t] * inv;
    row[t + 64] = Gsum[g * 128 + t + 64] * inv;
    __syncthreads();
    float acc = b3[t];
    for (int k = 0; k < 128; ++k) acc += row[k] * W3[k * 64 + t];
    t1[t] = lrelu(acc);
    __syncthreads();
    acc = b4[t];
    for (int k = 0; k < 64; ++k) acc += t1[k] * W4[k * 64 + t];
    t2[t] = lrelu(acc);
    __syncthreads();
    if (t < 10) {
        acc = b5[t];
        for (int k = 0; k < 64; ++k) acc += t2[k] * W5[k * 10 + t];
        OUT[g * 10 + t] = acc;
    }
}

// ---------------------------------------------------------------------------

extern "C" void kernel_launch(void* const* d_in, const int* in_sizes, int n_in,
                              void* d_out, int out_size, void* d_ws, size_t ws_size,
                              hipStream_t stream) {
    const float* x    = (const float*)d_in[0];
    const int*   ei   = (const int*)d_in[1];   // [2, E] int32
    const int*   batch= (const int*)d_in[2];
    const float* W1   = (const float*)d_in[3];
    const float* b1   = (const float*)d_in[4];
    const float* W2   = (const float*)d_in[5];
    const float* b2   = (const float*)d_in[6];
    const float* W3   = (const float*)d_in[7];
    const float* b3   = (const float*)d_in[8];
    const float* W4   = (const float*)d_in[9];
    const float* b4   = (const float*)d_in[10];
    const float* W5   = (const float*)d_in[11];
    const float* b5   = (const float*)d_in[12];
    float* out = (float*)d_out;

    const int N = in_sizes[2];          // 100000
    const int E = in_sizes[1] / 2;      // 1600000
    const int NG = 128;                 // NUM_GRAPHS

    const int* src = ei;
    const int* dst = ei + E;

    // workspace carve-up  (degi, gsum, gcnt contiguous -> one zero pass)
    char* w = (char*)d_ws;
    unsigned short* bufA = (unsigned short*)w; w += (size_t)N * 128 * 2;  // 25.6 MB
    unsigned short* bufB = (unsigned short*)w; w += (size_t)N * 128 * 2;  // 25.6 MB
    int*   degi = (int*)w;   w += (size_t)N * 4;
    float* gsum = (float*)w; w += (size_t)NG * 128 * 4;
    int*   gcnt = (int*)w;   w += (size_t)NG * 4;
    float* dinv = (float*)w; w += (size_t)N * 4;
    int*   rp   = (int*)w;   w += (size_t)(N + 8) * 4;
    int*   bsum = (int*)w;   w += 512 * 4;
    int2*  csr2 = (int2*)w;  w += (size_t)(E + N) * 8;   // 13.6 MB
    int*   pos  = (int*)w;   w += (size_t)E * 4;         // 6.4 MB
    unsigned short* WT1 = (unsigned short*)w; w += 128 * 128 * 2;
    unsigned short* WT2 = (unsigned short*)w; w += 128 * 128 * 2;
    (void)ws_size; (void)n_in; (void)out_size;

    int nbN  = (N + 255) / 256;       // 391
    int nbE4 = (E / 4 + 255) / 256;   // 1563 (fill)
    int nbC  = (E + CEB - 1) / CEB;   // 98   (dense count)
    int nbG  = (N + 63) / 64;         // 1563 (gemm)
    int nZero = N + NG * 128 + NG;
    int nbZ  = (nZero + 255) / 256;

    // init: W prepack + zero accumulators
    k_init<<<128 + nbZ, 256, 0, stream>>>(degi, nZero, W1, WT1, W2, WT2);
    // CSR count (dense, 98 blocks) overlapped with GEMM layer 1
    k_count_gemm1<<<nbC + nbG, 256, 0, stream>>>(dst, degi, pos, E, nbC,
                                                 x, WT1, bufA, N);
    k_scan1<<<nbN, 256, 0, stream>>>(degi, rp, bsum, dinv, N);
    k_scan2<<<1, 512, 0, stream>>>(bsum, nbN);
    k_scan3<<<nbN, 256, 0, stream>>>(rp, bsum, N, E + N);
    k_fill_self<<<nbE4 + nbN, 256, 0, stream>>>(src, dst, pos, rp, dinv,
                                                csr2, E, nbE4, N);

    int nbA = (N + 3) / 4;            // 25000 agg blocks (4 waves = 4 nodes)

    // layer 1 aggregate, layer 2 gemm + aggregate
    k_agg5<<<nbA, 256, 0, stream>>>(bufA, csr2, rp, b1, bufB, N);
    k_gemm2<<<nbG, 256, 0, stream>>>(bufB, WT2, bufA, N);
    k_agg5<<<nbA, 256, 0, stream>>>(bufA, csr2, rp, b2, bufB, N);

    // pool + MLP head
    int nbP = (N + PCH - 1) / PCH;    // 782
    k_pool3<<<nbP, 256, 0, stream>>>(bufB, batch, gsum, gcnt, N);
    k_mlp<<<NG, 64, 0, stream>>>(gsum, gcnt, W3, b3, W4, b4, W5, b5, out);
}